// Round 2
// baseline (620.140 us; speedup 1.0000x reference)
//
#include <hip/hip_runtime.h>
#include <hip/hip_bf16.h>
#include <math.h>

// Rolled-coordinate pipeline (roll(-SH) folded into input cast, roll(+SH) into
// final store). M=4096 tokens, windows = contiguous 512-row blocks.

typedef __bf16 bf16x8 __attribute__((ext_vector_type(8)));
typedef float f32x4 __attribute__((ext_vector_type(4)));

#define ELEM4M 4194304ull   // 4096*1024
#define ELEM1M 1048576ull   // 1024*1024

__device__ __forceinline__ float b2f(short s) {
    unsigned u = ((unsigned)(unsigned short)s) << 16;
    float f; __builtin_memcpy(&f, &u, 4); return f;
}
__device__ __forceinline__ short f2b(float f) {
    unsigned u; __builtin_memcpy(&u, &f, 4);
    u = (u + 0x7fffu + ((u >> 16) & 1u)) >> 16;
    return (short)u;
}

// ---------------- cast + roll inputs: rolled[b,t',l,d] = bf16(x[b,(t'+4)%32,l,d])
__global__ __launch_bounds__(256) void cast_roll_k(
    const float* __restrict__ a, const float* __restrict__ v,
    const float* __restrict__ im, short* __restrict__ dst)
{
    int z = blockIdx.y;
    const float* src = (z == 0) ? a : ((z == 1) ? v : im);
    int i = (blockIdx.x * 256 + threadIdx.x) * 4;
    int row = i >> 10, d = i & 1023;
    int b = row >> 11, tp = (row >> 6) & 31, l = row & 63;
    int srow = (b << 11) + (((tp + 4) & 31) << 6) + l;
    float4 val = *(const float4*)(src + (size_t)srow * 1024 + d);
    short4 o;
    o.x = f2b(val.x); o.y = f2b(val.y); o.z = f2b(val.z); o.w = f2b(val.w);
    *(short4*)(dst + (size_t)z * ELEM4M + i) = o;
}

// ---------------- weight transpose fp32->bf16: dst[n][k] = bf16(src[k][n])
__device__ __forceinline__ void transpose_body(const float* __restrict__ src,
                                               short* __restrict__ dst, int K, int N)
{
    __shared__ float tile[32][33];
    int x = blockIdx.x * 32 + threadIdx.x;
    int y0 = blockIdx.y * 32;
#pragma unroll
    for (int i = 0; i < 32; i += 8)
        tile[threadIdx.y + i][threadIdx.x] = src[(size_t)(y0 + threadIdx.y + i) * N + x];
    __syncthreads();
    int x2 = y0 + threadIdx.x;
    int y2 = blockIdx.x * 32 + threadIdx.y;
#pragma unroll
    for (int i = 0; i < 32; i += 8)
        dst[(size_t)(y2 + i) * K + x2] = f2b(tile[threadIdx.x][threadIdx.y + i]);
}

__global__ void transpose_qkvp_k(const float* Wq, const float* Wk, const float* Wv,
                                 const float* Wp, short* dst)
{
    int z = blockIdx.z;             // 0..11 : Wq0..2, Wk0..2, Wv0..2, Wp0..2
    int g = z / 3, j = z - g * 3;
    const float* s4[4] = {Wq, Wk, Wv, Wp};
    transpose_body(s4[g] + (size_t)j * ELEM1M, dst + (size_t)z * ELEM1M, 1024, 1024);
}

__global__ void transpose_wg1_k(const float* Wg1, short* dst)
{
    transpose_body(Wg1, dst, 3072, 2048);   // [3072][2048] -> [2048][3072]
}

// ---------------- bf16 V transpose: Vt[j][c][t] = V[j][t][c]
__global__ __launch_bounds__(256) void transpose_v_k(const short* __restrict__ V,
                                                     short* __restrict__ Vt)
{
    __shared__ short tile[64][65];
    int j = blockIdx.z;
    int c0 = blockIdx.x * 64, t0 = blockIdx.y * 64;
    const short* src = V + (size_t)j * ELEM4M;
    short* dst = Vt + (size_t)j * ELEM4M;
    int x = threadIdx.x & 63, y4 = threadIdx.x >> 6;
#pragma unroll
    for (int i = 0; i < 16; i++) {
        int row = y4 * 16 + i;
        tile[row][x] = src[(size_t)(t0 + row) * 1024 + c0 + x];
    }
    __syncthreads();
#pragma unroll
    for (int i = 0; i < 16; i++) {
        int row = y4 * 16 + i;
        dst[(size_t)(c0 + row) * 4096 + t0 + x] = tile[x][row];
    }
}

// ---------------- bf16 GEMM with async global->LDS staging (m97 structure).
// C[M,N] = act(A[M,K] @ W[K,N] + bias), W given as Wt[N][K].
// 128x128 tile, 4 waves each 64x64. Optional fused RMS-norm over the wave's
// 64-col span (== one head) with weight nw[64] and extra scale nscale.
template<bool GELU, bool RES>
__device__ __forceinline__ void gemm_core(
    const short* __restrict__ A, const short* __restrict__ Wt,
    const float* __restrict__ bias, const short* __restrict__ Res,
    const float* __restrict__ nw, float nscale,
    short* __restrict__ C, int ldc, int colOff, int Ksz)
{
    __shared__ __align__(16) short As[128 * 32];   // unpadded: global_load_lds lane order
    __shared__ __align__(16) short Bs[128 * 32];
    const int tid = threadIdx.x;
    const int wave = tid >> 6, lane = tid & 63, quad = lane >> 4, l15 = lane & 15;
    const int wm = (wave & 1) * 64, wn = (wave >> 1) * 64;
    const int row0 = blockIdx.x * 128, col0 = blockIdx.y * 128;
    const int crow = lane >> 2, cseg = lane & 3;   // 16 rows x 4 segs of 16B

    auto* As3 = (__attribute__((address_space(3))) short*)As;
    auto* Bs3 = (__attribute__((address_space(3))) short*)Bs;

    f32x4 acc[4][4];
#pragma unroll
    for (int i = 0; i < 4; i++)
#pragma unroll
        for (int jj = 0; jj < 4; jj++) acc[i][jj] = f32x4{0.f, 0.f, 0.f, 0.f};

    for (int k0 = 0; k0 < Ksz; k0 += 32) {
#pragma unroll
        for (int half = 0; half < 2; half++) {
            int chunk = wave + half * 4;           // wave-uniform
            const short* ga = A + (size_t)(row0 + chunk * 16 + crow) * Ksz + k0 + cseg * 8;
            const short* gb = Wt + (size_t)(col0 + chunk * 16 + crow) * Ksz + k0 + cseg * 8;
            __builtin_amdgcn_global_load_lds(
                (const __attribute__((address_space(1))) void*)ga,
                (__attribute__((address_space(3))) void*)(As3 + chunk * 512), 16, 0, 0);
            __builtin_amdgcn_global_load_lds(
                (const __attribute__((address_space(1))) void*)gb,
                (__attribute__((address_space(3))) void*)(Bs3 + chunk * 512), 16, 0, 0);
        }
        __syncthreads();
        bf16x8 af[4], bfr[4];
#pragma unroll
        for (int mi = 0; mi < 4; mi++)
            af[mi] = *(const bf16x8*)(As + (wm + mi * 16 + l15) * 32 + quad * 8);
#pragma unroll
        for (int ni = 0; ni < 4; ni++)
            bfr[ni] = *(const bf16x8*)(Bs + (wn + ni * 16 + l15) * 32 + quad * 8);
#pragma unroll
        for (int mi = 0; mi < 4; mi++)
#pragma unroll
            for (int ni = 0; ni < 4; ni++)
                acc[mi][ni] = __builtin_amdgcn_mfma_f32_16x16x32_bf16(
                    af[mi], bfr[ni], acc[mi][ni], 0, 0, 0);
        __syncthreads();
    }

    float bv4[4];
#pragma unroll
    for (int ni = 0; ni < 4; ni++) bv4[ni] = bias[col0 + wn + ni * 16 + l15];

    if (nw != nullptr) {
        // fused RMS over head_dim: wave's 64 cols == one head; hd = ni*16+l15
        float w4[4];
#pragma unroll
        for (int ni = 0; ni < 4; ni++) w4[ni] = nw[ni * 16 + l15];
#pragma unroll
        for (int mi = 0; mi < 4; mi++)
#pragma unroll
            for (int r = 0; r < 4; r++) {
                float v0 = acc[mi][0][r] + bv4[0];
                float v1 = acc[mi][1][r] + bv4[1];
                float v2 = acc[mi][2][r] + bv4[2];
                float v3 = acc[mi][3][r] + bv4[3];
                float ss = v0 * v0 + v1 * v1 + v2 * v2 + v3 * v3;
                ss += __shfl_xor(ss, 1); ss += __shfl_xor(ss, 2);
                ss += __shfl_xor(ss, 4); ss += __shfl_xor(ss, 8);
                float sc = rsqrtf(ss * (1.0f / 64.0f) + 1e-6f) * nscale;
                int row = row0 + wm + mi * 16 + quad * 4 + r;
                short* cp = C + (size_t)row * ldc + colOff + col0 + wn + l15;
                cp[0]  = f2b(v0 * sc * w4[0]);
                cp[16] = f2b(v1 * sc * w4[1]);
                cp[32] = f2b(v2 * sc * w4[2]);
                cp[48] = f2b(v3 * sc * w4[3]);
            }
    } else {
#pragma unroll
        for (int mi = 0; mi < 4; mi++)
#pragma unroll
            for (int ni = 0; ni < 4; ni++) {
                int col = col0 + wn + ni * 16 + l15;
#pragma unroll
                for (int r = 0; r < 4; r++) {
                    int row = row0 + wm + mi * 16 + quad * 4 + r;
                    float v = acc[mi][ni][r] + bv4[ni];
                    if (GELU) v = 0.5f * v * (1.0f + erff(v * 0.70710678118f));
                    if (RES)  v += b2f(Res[(size_t)row * 1024 + col]);
                    C[(size_t)row * ldc + colOff + col] = f2b(v);
                }
            }
    }
}

__global__ __launch_bounds__(256) void gemm_qkv_k(
    const short* r0, const short* r1, const short* r2,
    const short* Wt, const float* bq, const float* bk, const float* bv,
    const float* qn, const float* kn, short* qkv)
{
    int z = blockIdx.z;           // 0..8 : Q0..2, K0..2, V0..2
    int g = z / 3, j = z - g * 3;
    const short* rolled[3] = {r0, r1, r2};
    const int kvmap[3] = {1, 0, 1};   // kv modality: video, audio, video
    const short* A = (g == 0) ? rolled[j] : rolled[kvmap[j]];
    const float* bias = ((g == 0) ? bq : ((g == 1) ? bk : bv)) + j * 1024;
    const float* nw = (g == 0) ? (qn + j * 64) : ((g == 1) ? (kn + j * 64) : nullptr);
    float nscale = (g == 0) ? 0.125f : 1.0f;   // fold HD^-0.5 into Q
    gemm_core<false, false>(A, Wt + (size_t)z * ELEM1M, bias, nullptr, nw, nscale,
                            qkv + (size_t)z * ELEM4M, 1024, 0, 1024);
}

__global__ __launch_bounds__(256) void gemm_out_k(
    const short* attnO, const short* Wt9, const float* bp,
    const short* r0, const short* r1, const short* r2, short* fcat)
{
    int j = blockIdx.z;
    const short* rolled[3] = {r0, r1, r2};
    gemm_core<false, true>(attnO + (size_t)j * ELEM4M, Wt9 + (size_t)j * ELEM1M,
                           bp + j * 1024, rolled[j], nullptr, 1.0f, fcat, 3072, j * 1024, 1024);
}

__global__ __launch_bounds__(256) void gemm_gate_k(
    const short* fcat, const short* Wg1t, const float* bg1, short* g1)
{
    gemm_core<true, false>(fcat, Wg1t, bg1, nullptr, nullptr, 1.0f, g1, 2048, 0, 3072);
}

// ---------------- attention: no K/V/Q LDS staging, no barriers, no running max.
// qn=kn=1 => post-RMS |q|=|k|=8 => |score| <= 8 (+small bias): exp() safe in fp32.
// Block = (qt, win*h, j); 4 waves x 16 q-rows. P round-trips per-wave LDS only.
__global__ __launch_bounds__(256) void attn_k(
    const short* __restrict__ qkv, const short* __restrict__ Vt,
    const float* __restrict__ rpb, short* __restrict__ attnO)
{
    const int qt = blockIdx.x;
    const int win = blockIdx.y >> 4, h = blockIdx.y & 15;
    const int j = blockIdx.z;
    const int tid = threadIdx.x, wave = tid >> 6, lane = tid & 63;
    const int quad = lane >> 4, l15 = lane & 15;

    const short* Q = qkv + (size_t)j * ELEM4M
                   + (size_t)(win * 512 + qt * 64 + wave * 16) * 1024 + h * 64;
    const short* K = qkv + (size_t)(3 + j) * ELEM4M + (size_t)(win * 512) * 1024 + h * 64;
    const short* Vtj = Vt + (size_t)j * ELEM4M + (size_t)(h * 64) * 4096 + win * 512;

    __shared__ __align__(16) short Ps[4][16 * 72];
    short* Pw = Ps[wave];

    bf16x8 qa[2];
    qa[0] = *(const bf16x8*)(Q + l15 * 1024 + quad * 8);
    qa[1] = *(const bf16x8*)(Q + l15 * 1024 + 32 + quad * 8);

    f32x4 oacc[4];
#pragma unroll
    for (int ni = 0; ni < 4; ni++) oacc[ni] = f32x4{0.f, 0.f, 0.f, 0.f};
    float psum[4] = {0.f, 0.f, 0.f, 0.f};
    const float* rpbj = rpb + j * 240;

    for (int kt = 0; kt < 8; kt++) {
        const short* Kt = K + (size_t)(kt * 64) * 1024;
        f32x4 sacc[4];
#pragma unroll
        for (int ni = 0; ni < 4; ni++) sacc[ni] = f32x4{0.f, 0.f, 0.f, 0.f};
#pragma unroll
        for (int ks = 0; ks < 2; ks++)
#pragma unroll
            for (int ni = 0; ni < 4; ni++) {
                bf16x8 kb = *(const bf16x8*)(Kt + (size_t)(ni * 16 + l15) * 1024
                                             + ks * 32 + quad * 8);
                sacc[ni] = __builtin_amdgcn_mfma_f32_16x16x32_bf16(qa[ks], kb, sacc[ni], 0, 0, 0);
            }

        float bv = rpbj[(qt - kt + 7) * 16 + h];
#pragma unroll
        for (int r = 0; r < 4; r++)
#pragma unroll
            for (int ni = 0; ni < 4; ni++) {
                float p = __expf(sacc[ni][r] + bv);
                psum[r] += p;
                Pw[(quad * 4 + r) * 72 + ni * 16 + l15] = f2b(p);
            }

        // per-wave LDS only: compiler inserts lgkmcnt wait, no barrier needed
#pragma unroll
        for (int ks = 0; ks < 2; ks++) {
            bf16x8 pa = *(const bf16x8*)(Pw + l15 * 72 + ks * 32 + quad * 8);
#pragma unroll
            for (int ni = 0; ni < 4; ni++) {
                bf16x8 vb = *(const bf16x8*)(Vtj + (size_t)(ni * 16 + l15) * 4096
                                             + kt * 64 + ks * 32 + quad * 8);
                oacc[ni] = __builtin_amdgcn_mfma_f32_16x16x32_bf16(pa, vb, oacc[ni], 0, 0, 0);
            }
        }
    }

#pragma unroll
    for (int r = 0; r < 4; r++) {
        float s = psum[r];
        s += __shfl_xor(s, 1); s += __shfl_xor(s, 2);
        s += __shfl_xor(s, 4); s += __shfl_xor(s, 8);
        psum[r] = 1.0f / s;
    }

    short* Op = attnO + (size_t)j * ELEM4M;
#pragma unroll
    for (int ni = 0; ni < 4; ni++)
#pragma unroll
        for (int r = 0; r < 4; r++) {
            int row = win * 512 + qt * 64 + wave * 16 + quad * 4 + r;
            int col = h * 64 + ni * 16 + l15;
            Op[(size_t)row * 1024 + col] = f2b(oacc[ni][r] * psum[r]);
        }
}

// ---------------- gate dot (g1 @ Wg2 + bg2), softmax-3, fuse, un-roll store
__global__ __launch_bounds__(256) void fuse_k(
    const short* __restrict__ g1, const short* __restrict__ fcat,
    const float* __restrict__ Wg2, const float* __restrict__ bg2,
    float* __restrict__ out)
{
    int row = blockIdx.x, tid = threadIdx.x;
    const short* gp = g1 + (size_t)row * 2048;
    float a0 = 0.f, a1 = 0.f, a2 = 0.f;
    for (int k = tid; k < 2048; k += 256) {
        float gv = b2f(gp[k]);
        a0 += gv * Wg2[k * 3 + 0];
        a1 += gv * Wg2[k * 3 + 1];
        a2 += gv * Wg2[k * 3 + 2];
    }
#pragma unroll
    for (int off = 1; off < 64; off <<= 1) {
        a0 += __shfl_xor(a0, off); a1 += __shfl_xor(a1, off); a2 += __shfl_xor(a2, off);
    }
    __shared__ float part[4][3];
    int wave = tid >> 6, lane = tid & 63;
    if (lane == 0) { part[wave][0] = a0; part[wave][1] = a1; part[wave][2] = a2; }
    __syncthreads();
    float g0 = part[0][0] + part[1][0] + part[2][0] + part[3][0] + bg2[0];
    float gA = part[0][1] + part[1][1] + part[2][1] + part[3][1] + bg2[1];
    float gB = part[0][2] + part[1][2] + part[2][2] + part[3][2] + bg2[2];
    float mx = fmaxf(g0, fmaxf(gA, gB));
    float e0 = __expf(g0 - mx), e1 = __expf(gA - mx), e2 = __expf(gB - mx);
    float inv = 1.0f / (e0 + e1 + e2);
    e0 *= inv; e1 *= inv; e2 *= inv;

    int b = row >> 11, tp = (row >> 6) & 31, l = row & 63;
    size_t orow = (size_t)(b * 32 + ((tp + 4) & 31)) * 64 + l;   // un-roll (+SH)
    const short* f0 = fcat + (size_t)row * 3072;
    float* op = out + orow * 1024;
    for (int c = tid; c < 1024; c += 256)
        op[c] = e0 * b2f(f0[c]) + e1 * b2f(f0[1024 + c]) + e2 * b2f(f0[2048 + c]);
}

extern "C" void kernel_launch(void* const* d_in, const int* in_sizes, int n_in,
                              void* d_out, int out_size, void* d_ws, size_t ws_size,
                              hipStream_t stream)
{
    const float* audio = (const float*)d_in[0];
    const float* video = (const float*)d_in[1];
    const float* image = (const float*)d_in[2];
    const float* Wq = (const float*)d_in[3];
    const float* Wk = (const float*)d_in[4];
    const float* Wv = (const float*)d_in[5];
    const float* Wp = (const float*)d_in[6];
    const float* bq = (const float*)d_in[7];
    const float* bk = (const float*)d_in[8];
    const float* bv = (const float*)d_in[9];
    const float* bp = (const float*)d_in[10];
    const float* qn = (const float*)d_in[11];
    const float* kn = (const float*)d_in[12];
    const float* rpb = (const float*)d_in[13];
    const float* Wg1 = (const float*)d_in[14];
    const float* bg1 = (const float*)d_in[15];
    const float* Wg2 = (const float*)d_in[16];
    const float* bg2 = (const float*)d_in[17];
    float* out = (float*)d_out;

    short* ws = (short*)d_ws;
    short* rolled = ws;                                  // 3 * 4M
    short* Wt     = rolled + 3 * ELEM4M;                 // 12 * 1M
    short* Wg1t   = Wt + 12 * ELEM1M;                    // 6M  [2048][3072]
    short* qkv    = Wg1t + 6 * ELEM1M;                   // 9 * 4M (Q,K,V x3)
    short* attnO  = qkv + 9 * ELEM4M;                    // 3 * 4M
    short* fcat   = attnO + 3 * ELEM4M;                  // 4096*3072
    short* VtBuf  = fcat;                                // overlay: Vt dead before fcat written
    short* g1buf  = qkv;                                 // overlay: qkv dead after attn

    cast_roll_k<<<dim3(4096, 3), 256, 0, stream>>>(audio, video, image, rolled);
    transpose_qkvp_k<<<dim3(32, 32, 12), dim3(32, 8), 0, stream>>>(Wq, Wk, Wv, Wp, Wt);
    transpose_wg1_k<<<dim3(64, 96), dim3(32, 8), 0, stream>>>(Wg1, Wg1t);
    gemm_qkv_k<<<dim3(32, 8, 9), 256, 0, stream>>>(
        rolled, rolled + ELEM4M, rolled + 2 * ELEM4M, Wt, bq, bk, bv, qn, kn, qkv);
    transpose_v_k<<<dim3(16, 64, 3), 256, 0, stream>>>(qkv + 6 * ELEM4M, VtBuf);
    attn_k<<<dim3(8, 128, 3), 256, 0, stream>>>(qkv, VtBuf, rpb, attnO);
    gemm_out_k<<<dim3(32, 8, 3), 256, 0, stream>>>(
        attnO, Wt + 9 * ELEM1M, bp, rolled, rolled + ELEM4M, rolled + 2 * ELEM4M, fcat);
    gemm_gate_k<<<dim3(32, 16), 256, 0, stream>>>(fcat, Wg1t, bg1, g1buf);
    fuse_k<<<4096, 256, 0, stream>>>(g1buf, Wg1t /*unused-safe*/ == nullptr ? nullptr : fcat, Wg2, bg2, out);
}

// Round 3
// 486.481 us; speedup vs baseline: 1.2747x; 1.2747x over previous
//
#include <hip/hip_runtime.h>
#include <hip/hip_bf16.h>
#include <math.h>

// Rolled-coordinate pipeline (roll(-SH) folded into input cast, roll(+SH) into
// final store). M=4096 tokens, windows = contiguous 512-row blocks.

typedef __bf16 bf16x8 __attribute__((ext_vector_type(8)));
typedef float f32x4 __attribute__((ext_vector_type(4)));

#define ELEM4M 4194304ull   // 4096*1024
#define ELEM1M 1048576ull   // 1024*1024

__device__ __forceinline__ float b2f(short s) {
    unsigned u = ((unsigned)(unsigned short)s) << 16;
    float f; __builtin_memcpy(&f, &u, 4); return f;
}
__device__ __forceinline__ short f2b(float f) {
    unsigned u; __builtin_memcpy(&u, &f, 4);
    u = (u + 0x7fffu + ((u >> 16) & 1u)) >> 16;
    return (short)u;
}

// ---------------- cast + roll inputs: rolled[b,t',l,d] = bf16(x[b,(t'+4)%32,l,d])
__global__ __launch_bounds__(256) void cast_roll_k(
    const float* __restrict__ a, const float* __restrict__ v,
    const float* __restrict__ im, short* __restrict__ dst)
{
    int z = blockIdx.y;
    const float* src = (z == 0) ? a : ((z == 1) ? v : im);
    int i = (blockIdx.x * 256 + threadIdx.x) * 4;
    int row = i >> 10, d = i & 1023;
    int b = row >> 11, tp = (row >> 6) & 31, l = row & 63;
    int srow = (b << 11) + (((tp + 4) & 31) << 6) + l;
    float4 val = *(const float4*)(src + (size_t)srow * 1024 + d);
    short4 o;
    o.x = f2b(val.x); o.y = f2b(val.y); o.z = f2b(val.z); o.w = f2b(val.w);
    *(short4*)(dst + (size_t)z * ELEM4M + i) = o;
}

// ---------------- weight transpose fp32->bf16: dst[n][k] = bf16(src[k][n])
__device__ __forceinline__ void transpose_body(const float* __restrict__ src,
                                               short* __restrict__ dst, int K, int N)
{
    __shared__ float tile[32][33];
    int x = blockIdx.x * 32 + threadIdx.x;
    int y0 = blockIdx.y * 32;
#pragma unroll
    for (int i = 0; i < 32; i += 8)
        tile[threadIdx.y + i][threadIdx.x] = src[(size_t)(y0 + threadIdx.y + i) * N + x];
    __syncthreads();
    int x2 = y0 + threadIdx.x;
    int y2 = blockIdx.x * 32 + threadIdx.y;
#pragma unroll
    for (int i = 0; i < 32; i += 8)
        dst[(size_t)(y2 + i) * K + x2] = f2b(tile[threadIdx.x][threadIdx.y + i]);
}

__global__ void transpose_qkvp_k(const float* Wq, const float* Wk, const float* Wv,
                                 const float* Wp, short* dst)
{
    int z = blockIdx.z;             // 0..11 : Wq0..2, Wk0..2, Wv0..2, Wp0..2
    int g = z / 3, j = z - g * 3;
    const float* s4[4] = {Wq, Wk, Wv, Wp};
    transpose_body(s4[g] + (size_t)j * ELEM1M, dst + (size_t)z * ELEM1M, 1024, 1024);
}

__global__ void transpose_wg1_k(const float* Wg1, short* dst)
{
    transpose_body(Wg1, dst, 3072, 2048);   // [3072][2048] -> [2048][3072]
}

// ---------------- bf16 V transpose: Vt[j][c][t] = V[j][t][c]
__global__ __launch_bounds__(256) void transpose_v_k(const short* __restrict__ V,
                                                     short* __restrict__ Vt)
{
    __shared__ short tile[64][65];
    int j = blockIdx.z;
    int c0 = blockIdx.x * 64, t0 = blockIdx.y * 64;
    const short* src = V + (size_t)j * ELEM4M;
    short* dst = Vt + (size_t)j * ELEM4M;
    int x = threadIdx.x & 63, y4 = threadIdx.x >> 6;
#pragma unroll
    for (int i = 0; i < 16; i++) {
        int row = y4 * 16 + i;
        tile[row][x] = src[(size_t)(t0 + row) * 1024 + c0 + x];
    }
    __syncthreads();
#pragma unroll
    for (int i = 0; i < 16; i++) {
        int row = y4 * 16 + i;
        dst[(size_t)(c0 + row) * 4096 + t0 + x] = tile[x][row];
    }
}

// ---------------- bf16 GEMM with async global->LDS staging (m97 structure).
template<bool GELU, bool RES>
__device__ __forceinline__ void gemm_core(
    const short* __restrict__ A, const short* __restrict__ Wt,
    const float* __restrict__ bias, const short* __restrict__ Res,
    const float* __restrict__ nw, float nscale,
    short* __restrict__ C, int ldc, int colOff, int Ksz)
{
    __shared__ __align__(16) short As[128 * 32];
    __shared__ __align__(16) short Bs[128 * 32];
    const int tid = threadIdx.x;
    const int wave = tid >> 6, lane = tid & 63, quad = lane >> 4, l15 = lane & 15;
    const int wm = (wave & 1) * 64, wn = (wave >> 1) * 64;
    const int row0 = blockIdx.x * 128, col0 = blockIdx.y * 128;
    const int crow = lane >> 2, cseg = lane & 3;

    auto* As3 = (__attribute__((address_space(3))) short*)As;
    auto* Bs3 = (__attribute__((address_space(3))) short*)Bs;

    f32x4 acc[4][4];
#pragma unroll
    for (int i = 0; i < 4; i++)
#pragma unroll
        for (int jj = 0; jj < 4; jj++) acc[i][jj] = f32x4{0.f, 0.f, 0.f, 0.f};

    for (int k0 = 0; k0 < Ksz; k0 += 32) {
#pragma unroll
        for (int half = 0; half < 2; half++) {
            int chunk = wave + half * 4;
            const short* ga = A + (size_t)(row0 + chunk * 16 + crow) * Ksz + k0 + cseg * 8;
            const short* gb = Wt + (size_t)(col0 + chunk * 16 + crow) * Ksz + k0 + cseg * 8;
            __builtin_amdgcn_global_load_lds(
                (const __attribute__((address_space(1))) void*)ga,
                (__attribute__((address_space(3))) void*)(As3 + chunk * 512), 16, 0, 0);
            __builtin_amdgcn_global_load_lds(
                (const __attribute__((address_space(1))) void*)gb,
                (__attribute__((address_space(3))) void*)(Bs3 + chunk * 512), 16, 0, 0);
        }
        __syncthreads();
        bf16x8 af[4], bfr[4];
#pragma unroll
        for (int mi = 0; mi < 4; mi++)
            af[mi] = *(const bf16x8*)(As + (wm + mi * 16 + l15) * 32 + quad * 8);
#pragma unroll
        for (int ni = 0; ni < 4; ni++)
            bfr[ni] = *(const bf16x8*)(Bs + (wn + ni * 16 + l15) * 32 + quad * 8);
#pragma unroll
        for (int mi = 0; mi < 4; mi++)
#pragma unroll
            for (int ni = 0; ni < 4; ni++)
                acc[mi][ni] = __builtin_amdgcn_mfma_f32_16x16x32_bf16(
                    af[mi], bfr[ni], acc[mi][ni], 0, 0, 0);
        __syncthreads();
    }

    float bv4[4];
#pragma unroll
    for (int ni = 0; ni < 4; ni++) bv4[ni] = bias[col0 + wn + ni * 16 + l15];

    if (nw != nullptr) {
        float w4[4];
#pragma unroll
        for (int ni = 0; ni < 4; ni++) w4[ni] = nw[ni * 16 + l15];
#pragma unroll
        for (int mi = 0; mi < 4; mi++)
#pragma unroll
            for (int r = 0; r < 4; r++) {
                float v0 = acc[mi][0][r] + bv4[0];
                float v1 = acc[mi][1][r] + bv4[1];
                float v2 = acc[mi][2][r] + bv4[2];
                float v3 = acc[mi][3][r] + bv4[3];
                float ss = v0 * v0 + v1 * v1 + v2 * v2 + v3 * v3;
                ss += __shfl_xor(ss, 1); ss += __shfl_xor(ss, 2);
                ss += __shfl_xor(ss, 4); ss += __shfl_xor(ss, 8);
                float sc = rsqrtf(ss * (1.0f / 64.0f) + 1e-6f) * nscale;
                int row = row0 + wm + mi * 16 + quad * 4 + r;
                short* cp = C + (size_t)row * ldc + colOff + col0 + wn + l15;
                cp[0]  = f2b(v0 * sc * w4[0]);
                cp[16] = f2b(v1 * sc * w4[1]);
                cp[32] = f2b(v2 * sc * w4[2]);
                cp[48] = f2b(v3 * sc * w4[3]);
            }
    } else {
#pragma unroll
        for (int mi = 0; mi < 4; mi++)
#pragma unroll
            for (int ni = 0; ni < 4; ni++) {
                int col = col0 + wn + ni * 16 + l15;
#pragma unroll
                for (int r = 0; r < 4; r++) {
                    int row = row0 + wm + mi * 16 + quad * 4 + r;
                    float v = acc[mi][ni][r] + bv4[ni];
                    if (GELU) v = 0.5f * v * (1.0f + erff(v * 0.70710678118f));
                    if (RES)  v += b2f(Res[(size_t)row * 1024 + col]);
                    C[(size_t)row * ldc + colOff + col] = f2b(v);
                }
            }
    }
}

__global__ __launch_bounds__(256) void gemm_qkv_k(
    const short* r0, const short* r1, const short* r2,
    const short* Wt, const float* bq, const float* bk, const float* bv,
    const float* qn, const float* kn, short* qkv)
{
    int z = blockIdx.z;           // 0..8 : Q0..2, K0..2, V0..2
    int g = z / 3, j = z - g * 3;
    const short* rolled[3] = {r0, r1, r2};
    const int kvmap[3] = {1, 0, 1};
    const short* A = (g == 0) ? rolled[j] : rolled[kvmap[j]];
    const float* bias = ((g == 0) ? bq : ((g == 1) ? bk : bv)) + j * 1024;
    const float* nw = (g == 0) ? (qn + j * 64) : ((g == 1) ? (kn + j * 64) : nullptr);
    float nscale = (g == 0) ? 0.125f : 1.0f;
    gemm_core<false, false>(A, Wt + (size_t)z * ELEM1M, bias, nullptr, nw, nscale,
                            qkv + (size_t)z * ELEM4M, 1024, 0, 1024);
}

__global__ __launch_bounds__(256) void gemm_out_k(
    const short* attnO, const short* Wt9, const float* bp,
    const short* r0, const short* r1, const short* r2, short* fcat)
{
    int j = blockIdx.z;
    const short* rolled[3] = {r0, r1, r2};
    gemm_core<false, true>(attnO + (size_t)j * ELEM4M, Wt9 + (size_t)j * ELEM1M,
                           bp + j * 1024, rolled[j], nullptr, 1.0f, fcat, 3072, j * 1024, 1024);
}

__global__ __launch_bounds__(256) void gemm_gate_k(
    const short* fcat, const short* Wg1t, const float* bg1, short* g1)
{
    gemm_core<true, false>(fcat, Wg1t, bg1, nullptr, nullptr, 1.0f, g1, 2048, 0, 3072);
}

// ---------------- attention v3: block = (qhalf, win*h, j); 4 waves x 64 q-rows.
// K/V^T chunks (64 keys) staged in LDS via swizzled global_load_lds, shared by
// all 4 waves; staging for chunk ck+1 issued before compute of ck (overlap).
// S^T via swapped MFMA operands: lane holds 4 consecutive keys -> packed b64 P
// writes, in-register row sums. No running max (|score|<=8, exp safe in fp32).
__global__ __launch_bounds__(256, 2) void attn_k(
    const short* __restrict__ qkv, const short* __restrict__ Vt,
    const float* __restrict__ rpb, short* __restrict__ attnO)
{
    const int qhalf = blockIdx.x;
    const int win = blockIdx.y >> 4, h = blockIdx.y & 15;
    const int j = blockIdx.z;
    const int tid = threadIdx.x, wave = tid >> 6, lane = tid & 63;
    const int quad = lane >> 4, l15 = lane & 15;

    __shared__ __align__(16) short Ks[64 * 64];
    __shared__ __align__(16) short Vc[64 * 64];
    __shared__ __align__(16) short Ps[4][2][16 * 80];   // stride 80 shorts: 16B-aligned rows

    auto* Ks3 = (__attribute__((address_space(3))) short*)Ks;
    auto* Vc3 = (__attribute__((address_space(3))) short*)Vc;

    const int tq = qhalf * 4 + wave;            // this wave's q temporal step
    const int qrow0 = win * 512 + tq * 64;
    const short* Qb = qkv + (size_t)j * ELEM4M + (size_t)qrow0 * 1024 + h * 64;
    const short* Kb = qkv + (size_t)(3 + j) * ELEM4M + (size_t)(win * 512) * 1024 + h * 64;
    const short* Vb = Vt + (size_t)j * ELEM4M + (size_t)(h * 64) * 4096 + win * 512;

    // stage 64-key chunk: K rows (key-major) and Vt rows (hd-major), with the
    // 16B-chunk index XOR-swizzled by (row&7) on the GLOBAL side so the LDS
    // image reads back conflict-free.
    auto stage = [&](int ck) {
#pragma unroll
        for (int i = 0; i < 2; i++) {
            int s0 = (wave * 2 + i) * 64;            // wave-uniform base slot
            int slot = s0 + lane;
            int r = slot >> 3, sw = ((slot & 7) ^ (r & 7)) * 8;
            const short* gk = Kb + (size_t)(ck * 64 + r) * 1024 + sw;
            const short* gv = Vb + (size_t)r * 4096 + ck * 64 + sw;
            __builtin_amdgcn_global_load_lds(
                (const __attribute__((address_space(1))) void*)gk,
                (__attribute__((address_space(3))) void*)(Ks3 + s0 * 8), 16, 0, 0);
            __builtin_amdgcn_global_load_lds(
                (const __attribute__((address_space(1))) void*)gv,
                (__attribute__((address_space(3))) void*)(Vc3 + s0 * 8), 16, 0, 0);
        }
    };

    bf16x8 qa[4][2];
#pragma unroll
    for (int qt = 0; qt < 4; qt++)
#pragma unroll
        for (int ks = 0; ks < 2; ks++)
            qa[qt][ks] = *(const bf16x8*)(Qb + (size_t)(qt * 16 + l15) * 1024
                                          + ks * 32 + quad * 8);

    f32x4 oacc[4][4];
#pragma unroll
    for (int qt = 0; qt < 4; qt++)
#pragma unroll
        for (int on = 0; on < 4; on++) oacc[qt][on] = f32x4{0.f, 0.f, 0.f, 0.f};
    float psum[4] = {0.f, 0.f, 0.f, 0.f};
    const float* rpbj = rpb + j * 240;

    stage(0);
    for (int ck = 0; ck < 8; ck++) {
        __syncthreads();                         // staged chunk visible
        bf16x8 kb[4][2], vb[4][2];
        const int swz = (l15 & 7);
#pragma unroll
        for (int t = 0; t < 4; t++)
#pragma unroll
            for (int ks = 0; ks < 2; ks++) {
                int row = t * 16 + l15;
                int off = row * 64 + (((ks * 4 + quad) ^ swz) * 8);
                kb[t][ks] = *(const bf16x8*)(Ks + off);
                vb[t][ks] = *(const bf16x8*)(Vc + off);
            }
        __syncthreads();                         // all waves hoisted; safe to restage
        if (ck < 7) stage(ck + 1);               // overlap DMA with compute

        float bv = rpbj[(tq - ck + 7) * 16 + h];
#pragma unroll
        for (int qt = 0; qt < 4; qt++) {
            f32x4 sacc[4];
#pragma unroll
            for (int kn = 0; kn < 4; kn++) sacc[kn] = f32x4{0.f, 0.f, 0.f, 0.f};
#pragma unroll
            for (int ks = 0; ks < 2; ks++)
#pragma unroll
                for (int kn = 0; kn < 4; kn++)
                    sacc[kn] = __builtin_amdgcn_mfma_f32_16x16x32_bf16(
                        kb[kn][ks], qa[qt][ks], sacc[kn], 0, 0, 0);   // S^T tile

            short* Pw = &Ps[wave][qt & 1][0];
            float ps = 0.f;
#pragma unroll
            for (int kn = 0; kn < 4; kn++) {
                float p0 = __expf(sacc[kn][0] + bv);
                float p1 = __expf(sacc[kn][1] + bv);
                float p2 = __expf(sacc[kn][2] + bv);
                float p3 = __expf(sacc[kn][3] + bv);
                ps += (p0 + p1) + (p2 + p3);
                short4 pk;
                pk.x = f2b(p0); pk.y = f2b(p1); pk.z = f2b(p2); pk.w = f2b(p3);
                // lane holds P[q=l15][key = kn*16 + quad*4 .. +3]
                *(short4*)(Pw + l15 * 80 + kn * 16 + quad * 4) = pk;
            }
            psum[qt] += ps;
#pragma unroll
            for (int ks = 0; ks < 2; ks++) {
                bf16x8 pa = *(const bf16x8*)(Pw + l15 * 80 + ks * 32 + quad * 8);
#pragma unroll
                for (int on = 0; on < 4; on++)
                    oacc[qt][on] = __builtin_amdgcn_mfma_f32_16x16x32_bf16(
                        pa, vb[on][ks], oacc[qt][on], 0, 0, 0);
            }
        }
    }

    short* Op = attnO + (size_t)j * ELEM4M;
#pragma unroll
    for (int qt = 0; qt < 4; qt++) {
        float s = psum[qt];
        s += __shfl_xor(s, 16); s += __shfl_xor(s, 32);
        float inv = 1.0f / s;                    // valid at every lane for q-local=l15
        float invr[4];
#pragma unroll
        for (int r = 0; r < 4; r++) invr[r] = __shfl(inv, quad * 4 + r);
#pragma unroll
        for (int on = 0; on < 4; on++) {
            int col = h * 64 + on * 16 + l15;
#pragma unroll
            for (int r = 0; r < 4; r++) {
                int row = qrow0 + qt * 16 + quad * 4 + r;
                Op[(size_t)row * 1024 + col] = f2b(oacc[qt][on][r] * invr[r]);
            }
        }
    }
}

// ---------------- gate dot (g1 @ Wg2 + bg2), softmax-3, fuse, un-roll store
__global__ __launch_bounds__(256) void fuse_k(
    const short* __restrict__ g1, const short* __restrict__ fcat,
    const float* __restrict__ Wg2, const float* __restrict__ bg2,
    float* __restrict__ out)
{
    int row = blockIdx.x, tid = threadIdx.x;
    const short* gp = g1 + (size_t)row * 2048;
    float a0 = 0.f, a1 = 0.f, a2 = 0.f;
    for (int k = tid; k < 2048; k += 256) {
        float gv = b2f(gp[k]);
        a0 += gv * Wg2[k * 3 + 0];
        a1 += gv * Wg2[k * 3 + 1];
        a2 += gv * Wg2[k * 3 + 2];
    }
#pragma unroll
    for (int off = 1; off < 64; off <<= 1) {
        a0 += __shfl_xor(a0, off); a1 += __shfl_xor(a1, off); a2 += __shfl_xor(a2, off);
    }
    __shared__ float part[4][3];
    int wave = tid >> 6, lane = tid & 63;
    if (lane == 0) { part[wave][0] = a0; part[wave][1] = a1; part[wave][2] = a2; }
    __syncthreads();
    float g0 = part[0][0] + part[1][0] + part[2][0] + part[3][0] + bg2[0];
    float gA = part[0][1] + part[1][1] + part[2][1] + part[3][1] + bg2[1];
    float gB = part[0][2] + part[1][2] + part[2][2] + part[3][2] + bg2[2];
    float mx = fmaxf(g0, fmaxf(gA, gB));
    float e0 = __expf(g0 - mx), e1 = __expf(gA - mx), e2 = __expf(gB - mx);
    float inv = 1.0f / (e0 + e1 + e2);
    e0 *= inv; e1 *= inv; e2 *= inv;

    int b = row >> 11, tp = (row >> 6) & 31, l = row & 63;
    size_t orow = (size_t)(b * 32 + ((tp + 4) & 31)) * 64 + l;
    const short* f0 = fcat + (size_t)row * 3072;
    float* op = out + orow * 1024;
    for (int c = tid; c < 1024; c += 256)
        op[c] = e0 * b2f(f0[c]) + e1 * b2f(f0[1024 + c]) + e2 * b2f(f0[2048 + c]);
}

extern "C" void kernel_launch(void* const* d_in, const int* in_sizes, int n_in,
                              void* d_out, int out_size, void* d_ws, size_t ws_size,
                              hipStream_t stream)
{
    const float* audio = (const float*)d_in[0];
    const float* video = (const float*)d_in[1];
    const float* image = (const float*)d_in[2];
    const float* Wq = (const float*)d_in[3];
    const float* Wk = (const float*)d_in[4];
    const float* Wv = (const float*)d_in[5];
    const float* Wp = (const float*)d_in[6];
    const float* bq = (const float*)d_in[7];
    const float* bk = (const float*)d_in[8];
    const float* bv = (const float*)d_in[9];
    const float* bp = (const float*)d_in[10];
    const float* qn = (const float*)d_in[11];
    const float* kn = (const float*)d_in[12];
    const float* rpb = (const float*)d_in[13];
    const float* Wg1 = (const float*)d_in[14];
    const float* bg1 = (const float*)d_in[15];
    const float* Wg2 = (const float*)d_in[16];
    const float* bg2 = (const float*)d_in[17];
    float* out = (float*)d_out;

    short* ws = (short*)d_ws;
    short* rolled = ws;                                  // 3 * 4M
    short* Wt     = rolled + 3 * ELEM4M;                 // 12 * 1M
    short* Wg1t   = Wt + 12 * ELEM1M;                    // 6M  [2048][3072]
    short* qkv    = Wg1t + 6 * ELEM1M;                   // 9 * 4M (Q,K,V x3)
    short* attnO  = qkv + 9 * ELEM4M;                    // 3 * 4M
    short* fcat   = attnO + 3 * ELEM4M;                  // 4096*3072
    short* VtBuf  = fcat;                                // overlay: Vt dead before fcat written
    short* g1buf  = qkv;                                 // overlay: qkv dead after attn

    cast_roll_k<<<dim3(4096, 3), 256, 0, stream>>>(audio, video, image, rolled);
    transpose_qkvp_k<<<dim3(32, 32, 12), dim3(32, 8), 0, stream>>>(Wq, Wk, Wv, Wp, Wt);
    transpose_wg1_k<<<dim3(64, 96), dim3(32, 8), 0, stream>>>(Wg1, Wg1t);
    gemm_qkv_k<<<dim3(32, 8, 9), 256, 0, stream>>>(
        rolled, rolled + ELEM4M, rolled + 2 * ELEM4M, Wt, bq, bk, bv, qn, kn, qkv);
    transpose_v_k<<<dim3(16, 64, 3), 256, 0, stream>>>(qkv + 6 * ELEM4M, VtBuf);
    attn_k<<<dim3(2, 128, 3), 256, 0, stream>>>(qkv, VtBuf, rpb, attnO);
    gemm_out_k<<<dim3(32, 8, 3), 256, 0, stream>>>(
        attnO, Wt + 9 * ELEM1M, bp, rolled, rolled + ELEM4M, rolled + 2 * ELEM4M, fcat);
    gemm_gate_k<<<dim3(32, 16), 256, 0, stream>>>(fcat, Wg1t, bg1, g1buf);
    fuse_k<<<4096, 256, 0, stream>>>(g1buf, fcat, Wg2, bg2, out);
}

// Round 4
// 432.060 us; speedup vs baseline: 1.4353x; 1.1260x over previous
//
#include <hip/hip_runtime.h>
#include <hip/hip_bf16.h>
#include <math.h>

// Rolled-coordinate pipeline (roll(-SH) folded into input cast, roll(+SH) into
// final store). M=4096 tokens, windows = contiguous 512-row blocks.

typedef __bf16 bf16x8 __attribute__((ext_vector_type(8)));
typedef float f32x4 __attribute__((ext_vector_type(4)));

#define ELEM4M 4194304ull   // 4096*1024
#define ELEM1M 1048576ull   // 1024*1024

__device__ __forceinline__ float b2f(short s) {
    unsigned u = ((unsigned)(unsigned short)s) << 16;
    float f; __builtin_memcpy(&f, &u, 4); return f;
}
__device__ __forceinline__ short f2b(float f) {
    unsigned u; __builtin_memcpy(&u, &f, 4);
    u = (u + 0x7fffu + ((u >> 16) & 1u)) >> 16;
    return (short)u;
}

// ---------------- cast + roll inputs: rolled[b,t',l,d] = bf16(x[b,(t'+4)%32,l,d])
__global__ __launch_bounds__(256) void cast_roll_k(
    const float* __restrict__ a, const float* __restrict__ v,
    const float* __restrict__ im, short* __restrict__ dst)
{
    int z = blockIdx.y;
    const float* src = (z == 0) ? a : ((z == 1) ? v : im);
    int i = (blockIdx.x * 256 + threadIdx.x) * 4;
    int row = i >> 10, d = i & 1023;
    int b = row >> 11, tp = (row >> 6) & 31, l = row & 63;
    int srow = (b << 11) + (((tp + 4) & 31) << 6) + l;
    float4 val = *(const float4*)(src + (size_t)srow * 1024 + d);
    short4 o;
    o.x = f2b(val.x); o.y = f2b(val.y); o.z = f2b(val.z); o.w = f2b(val.w);
    *(short4*)(dst + (size_t)z * ELEM4M + i) = o;
}

// ---------------- weight transpose fp32->bf16: dst[n][k] = bf16(src[k][n])
__device__ __forceinline__ void transpose_body(const float* __restrict__ src,
                                               short* __restrict__ dst, int K, int N)
{
    __shared__ float tile[32][33];
    int x = blockIdx.x * 32 + threadIdx.x;
    int y0 = blockIdx.y * 32;
#pragma unroll
    for (int i = 0; i < 32; i += 8)
        tile[threadIdx.y + i][threadIdx.x] = src[(size_t)(y0 + threadIdx.y + i) * N + x];
    __syncthreads();
    int x2 = y0 + threadIdx.x;
    int y2 = blockIdx.x * 32 + threadIdx.y;
#pragma unroll
    for (int i = 0; i < 32; i += 8)
        dst[(size_t)(y2 + i) * K + x2] = f2b(tile[threadIdx.x][threadIdx.y + i]);
}

__global__ void transpose_qkvp_k(const float* Wq, const float* Wk, const float* Wv,
                                 const float* Wp, short* dst)
{
    int z = blockIdx.z;             // 0..11 : Wq0..2, Wk0..2, Wv0..2, Wp0..2
    int g = z / 3, j = z - g * 3;
    const float* s4[4] = {Wq, Wk, Wv, Wp};
    transpose_body(s4[g] + (size_t)j * ELEM1M, dst + (size_t)z * ELEM1M, 1024, 1024);
}

__global__ void transpose_wg1_k(const float* Wg1, short* dst)
{
    transpose_body(Wg1, dst, 3072, 2048);   // [3072][2048] -> [2048][3072]
}

// ---------------- bf16 V transpose: Vt[j][c][t] = V[j][t][c]
__global__ __launch_bounds__(256) void transpose_v_k(const short* __restrict__ V,
                                                     short* __restrict__ Vt)
{
    __shared__ short tile[64][65];
    int j = blockIdx.z;
    int c0 = blockIdx.x * 64, t0 = blockIdx.y * 64;
    const short* src = V + (size_t)j * ELEM4M;
    short* dst = Vt + (size_t)j * ELEM4M;
    int x = threadIdx.x & 63, y4 = threadIdx.x >> 6;
#pragma unroll
    for (int i = 0; i < 16; i++) {
        int row = y4 * 16 + i;
        tile[row][x] = src[(size_t)(t0 + row) * 1024 + c0 + x];
    }
    __syncthreads();
#pragma unroll
    for (int i = 0; i < 16; i++) {
        int row = y4 * 16 + i;
        dst[(size_t)(c0 + row) * 4096 + t0 + x] = tile[x][row];
    }
}

// ---------------- bf16 GEMM, BK=64, XOR-swizzled LDS image, early async staging.
// C[M,N] = act(A[M,K] @ W[K,N] + bias), W given as Wt[N][K]. 128x128 tile,
// 4 waves x 64x64. LDS tile [128][64] shorts; 16B chunk c of row r holds global
// chunk c^(r&7) -> fragment ds_read_b128 lands on distinct banks (<=2-way).
template<bool GELU, bool RES>
__device__ __forceinline__ void gemm_core(
    const short* __restrict__ A, const short* __restrict__ Wt,
    const float* __restrict__ bias, const short* __restrict__ Res,
    const float* __restrict__ nw, float nscale,
    short* __restrict__ C, int ldc, int colOff, int Ksz)
{
    __shared__ __align__(16) short As[128 * 64];
    __shared__ __align__(16) short Bs[128 * 64];
    const int tid = threadIdx.x;
    const int wave = tid >> 6, lane = tid & 63, quad = lane >> 4, l15 = lane & 15;
    const int wm = (wave & 1) * 64, wn = (wave >> 1) * 64;
    const int row0 = blockIdx.x * 128, col0 = blockIdx.y * 128;

    auto* As3 = (__attribute__((address_space(3))) short*)As;
    auto* Bs3 = (__attribute__((address_space(3))) short*)Bs;

    // staging: slot s in [0,1024) -> LDS 16B chunk s; row r=s>>3, chunk c=s&7,
    // global chunk gc = c ^ (r&7).
    const int s_lane_r = ((wave * 64 + lane) >> 3);        // per-issue base adds i*256
    auto stage = [&](int k0) {
#pragma unroll
        for (int i = 0; i < 4; i++) {
            int s0 = i * 256 + wave * 64;                  // wave-uniform
            int slot = s0 + lane;
            int r = slot >> 3, c = slot & 7;
            int gc = (c ^ (r & 7)) * 8;
            const short* ga = A + (size_t)(row0 + r) * Ksz + k0 + gc;
            const short* gb = Wt + (size_t)(col0 + r) * Ksz + k0 + gc;
            __builtin_amdgcn_global_load_lds(
                (const __attribute__((address_space(1))) void*)ga,
                (__attribute__((address_space(3))) void*)(As3 + s0 * 8), 16, 0, 0);
            __builtin_amdgcn_global_load_lds(
                (const __attribute__((address_space(1))) void*)gb,
                (__attribute__((address_space(3))) void*)(Bs3 + s0 * 8), 16, 0, 0);
        }
    };

    f32x4 acc[4][4];
#pragma unroll
    for (int i = 0; i < 4; i++)
#pragma unroll
        for (int jj = 0; jj < 4; jj++) acc[i][jj] = f32x4{0.f, 0.f, 0.f, 0.f};

    const int swz = l15 & 7;
    stage(0);
    for (int k0 = 0; k0 < Ksz; k0 += 64) {
        __syncthreads();                                   // staged tile visible
        bf16x8 af[4][2], bfr[4][2];
#pragma unroll
        for (int mi = 0; mi < 4; mi++)
#pragma unroll
            for (int ks = 0; ks < 2; ks++) {
                int coff = ((ks * 4 + quad) ^ swz) * 8;
                af[mi][ks]  = *(const bf16x8*)(As + (wm + mi * 16 + l15) * 64 + coff);
                bfr[mi][ks] = *(const bf16x8*)(Bs + (wn + mi * 16 + l15) * 64 + coff);
            }
        __syncthreads();                                   // all frags hoisted
        if (k0 + 64 < Ksz) stage(k0 + 64);                 // DMA overlaps MFMA
#pragma unroll
        for (int ks = 0; ks < 2; ks++)
#pragma unroll
            for (int mi = 0; mi < 4; mi++)
#pragma unroll
                for (int ni = 0; ni < 4; ni++)
                    acc[mi][ni] = __builtin_amdgcn_mfma_f32_16x16x32_bf16(
                        af[mi][ks], bfr[ni][ks], acc[mi][ni], 0, 0, 0);
    }

    float bv4[4];
#pragma unroll
    for (int ni = 0; ni < 4; ni++) bv4[ni] = bias[col0 + wn + ni * 16 + l15];

    if (nw != nullptr) {
        float w4[4];
#pragma unroll
        for (int ni = 0; ni < 4; ni++) w4[ni] = nw[ni * 16 + l15];
#pragma unroll
        for (int mi = 0; mi < 4; mi++)
#pragma unroll
            for (int r = 0; r < 4; r++) {
                float v0 = acc[mi][0][r] + bv4[0];
                float v1 = acc[mi][1][r] + bv4[1];
                float v2 = acc[mi][2][r] + bv4[2];
                float v3 = acc[mi][3][r] + bv4[3];
                float ss = v0 * v0 + v1 * v1 + v2 * v2 + v3 * v3;
                ss += __shfl_xor(ss, 1); ss += __shfl_xor(ss, 2);
                ss += __shfl_xor(ss, 4); ss += __shfl_xor(ss, 8);
                float sc = rsqrtf(ss * (1.0f / 64.0f) + 1e-6f) * nscale;
                int row = row0 + wm + mi * 16 + quad * 4 + r;
                short* cp = C + (size_t)row * ldc + colOff + col0 + wn + l15;
                cp[0]  = f2b(v0 * sc * w4[0]);
                cp[16] = f2b(v1 * sc * w4[1]);
                cp[32] = f2b(v2 * sc * w4[2]);
                cp[48] = f2b(v3 * sc * w4[3]);
            }
    } else {
#pragma unroll
        for (int mi = 0; mi < 4; mi++)
#pragma unroll
            for (int ni = 0; ni < 4; ni++) {
                int col = col0 + wn + ni * 16 + l15;
#pragma unroll
                for (int r = 0; r < 4; r++) {
                    int row = row0 + wm + mi * 16 + quad * 4 + r;
                    float v = acc[mi][ni][r] + bv4[ni];
                    if (GELU) v = 0.5f * v * (1.0f + erff(v * 0.70710678118f));
                    if (RES)  v += b2f(Res[(size_t)row * 1024 + col]);
                    C[(size_t)row * ldc + colOff + col] = f2b(v);
                }
            }
    }
}

__global__ __launch_bounds__(256) void gemm_qkv_k(
    const short* r0, const short* r1, const short* r2,
    const short* Wt, const float* bq, const float* bk, const float* bv,
    const float* qn, const float* kn, short* qkv)
{
    int z = blockIdx.z;           // 0..8 : Q0..2, K0..2, V0..2
    int g = z / 3, j = z - g * 3;
    const short* rolled[3] = {r0, r1, r2};
    const int kvmap[3] = {1, 0, 1};
    const short* A = (g == 0) ? rolled[j] : rolled[kvmap[j]];
    const float* bias = ((g == 0) ? bq : ((g == 1) ? bk : bv)) + j * 1024;
    const float* nw = (g == 0) ? (qn + j * 64) : ((g == 1) ? (kn + j * 64) : nullptr);
    float nscale = (g == 0) ? 0.125f : 1.0f;
    gemm_core<false, false>(A, Wt + (size_t)z * ELEM1M, bias, nullptr, nw, nscale,
                            qkv + (size_t)z * ELEM4M, 1024, 0, 1024);
}

__global__ __launch_bounds__(256) void gemm_out_k(
    const short* attnO, const short* Wt9, const float* bp,
    const short* r0, const short* r1, const short* r2, short* fcat)
{
    int j = blockIdx.z;
    const short* rolled[3] = {r0, r1, r2};
    gemm_core<false, true>(attnO + (size_t)j * ELEM4M, Wt9 + (size_t)j * ELEM1M,
                           bp + j * 1024, rolled[j], nullptr, 1.0f, fcat, 3072, j * 1024, 1024);
}

__global__ __launch_bounds__(256) void gemm_gate_k(
    const short* fcat, const short* Wg1t, const float* bg1, short* g1)
{
    gemm_core<true, false>(fcat, Wg1t, bg1, nullptr, nullptr, 1.0f, g1, 2048, 0, 3072);
}

// ---------------- attention v3 (unchanged from R3): block = (qhalf, win*h, j).
__global__ __launch_bounds__(256, 2) void attn_k(
    const short* __restrict__ qkv, const short* __restrict__ Vt,
    const float* __restrict__ rpb, short* __restrict__ attnO)
{
    const int qhalf = blockIdx.x;
    const int win = blockIdx.y >> 4, h = blockIdx.y & 15;
    const int j = blockIdx.z;
    const int tid = threadIdx.x, wave = tid >> 6, lane = tid & 63;
    const int quad = lane >> 4, l15 = lane & 15;

    __shared__ __align__(16) short Ks[64 * 64];
    __shared__ __align__(16) short Vc[64 * 64];
    __shared__ __align__(16) short Ps[4][2][16 * 80];

    auto* Ks3 = (__attribute__((address_space(3))) short*)Ks;
    auto* Vc3 = (__attribute__((address_space(3))) short*)Vc;

    const int tq = qhalf * 4 + wave;
    const int qrow0 = win * 512 + tq * 64;
    const short* Qb = qkv + (size_t)j * ELEM4M + (size_t)qrow0 * 1024 + h * 64;
    const short* Kb = qkv + (size_t)(3 + j) * ELEM4M + (size_t)(win * 512) * 1024 + h * 64;
    const short* Vb = Vt + (size_t)j * ELEM4M + (size_t)(h * 64) * 4096 + win * 512;

    auto stage = [&](int ck) {
#pragma unroll
        for (int i = 0; i < 2; i++) {
            int s0 = (wave * 2 + i) * 64;
            int slot = s0 + lane;
            int r = slot >> 3, sw = ((slot & 7) ^ (r & 7)) * 8;
            const short* gk = Kb + (size_t)(ck * 64 + r) * 1024 + sw;
            const short* gv = Vb + (size_t)r * 4096 + ck * 64 + sw;
            __builtin_amdgcn_global_load_lds(
                (const __attribute__((address_space(1))) void*)gk,
                (__attribute__((address_space(3))) void*)(Ks3 + s0 * 8), 16, 0, 0);
            __builtin_amdgcn_global_load_lds(
                (const __attribute__((address_space(1))) void*)gv,
                (__attribute__((address_space(3))) void*)(Vc3 + s0 * 8), 16, 0, 0);
        }
    };

    bf16x8 qa[4][2];
#pragma unroll
    for (int qt = 0; qt < 4; qt++)
#pragma unroll
        for (int ks = 0; ks < 2; ks++)
            qa[qt][ks] = *(const bf16x8*)(Qb + (size_t)(qt * 16 + l15) * 1024
                                          + ks * 32 + quad * 8);

    f32x4 oacc[4][4];
#pragma unroll
    for (int qt = 0; qt < 4; qt++)
#pragma unroll
        for (int on = 0; on < 4; on++) oacc[qt][on] = f32x4{0.f, 0.f, 0.f, 0.f};
    float psum[4] = {0.f, 0.f, 0.f, 0.f};
    const float* rpbj = rpb + j * 240;

    stage(0);
    for (int ck = 0; ck < 8; ck++) {
        __syncthreads();
        bf16x8 kb[4][2], vb[4][2];
        const int swz = (l15 & 7);
#pragma unroll
        for (int t = 0; t < 4; t++)
#pragma unroll
            for (int ks = 0; ks < 2; ks++) {
                int row = t * 16 + l15;
                int off = row * 64 + (((ks * 4 + quad) ^ swz) * 8);
                kb[t][ks] = *(const bf16x8*)(Ks + off);
                vb[t][ks] = *(const bf16x8*)(Vc + off);
            }
        __syncthreads();
        if (ck < 7) stage(ck + 1);

        float bv = rpbj[(tq - ck + 7) * 16 + h];
#pragma unroll
        for (int qt = 0; qt < 4; qt++) {
            f32x4 sacc[4];
#pragma unroll
            for (int kn = 0; kn < 4; kn++) sacc[kn] = f32x4{0.f, 0.f, 0.f, 0.f};
#pragma unroll
            for (int ks = 0; ks < 2; ks++)
#pragma unroll
                for (int kn = 0; kn < 4; kn++)
                    sacc[kn] = __builtin_amdgcn_mfma_f32_16x16x32_bf16(
                        kb[kn][ks], qa[qt][ks], sacc[kn], 0, 0, 0);

            short* Pw = &Ps[wave][qt & 1][0];
            float ps = 0.f;
#pragma unroll
            for (int kn = 0; kn < 4; kn++) {
                float p0 = __expf(sacc[kn][0] + bv);
                float p1 = __expf(sacc[kn][1] + bv);
                float p2 = __expf(sacc[kn][2] + bv);
                float p3 = __expf(sacc[kn][3] + bv);
                ps += (p0 + p1) + (p2 + p3);
                short4 pk;
                pk.x = f2b(p0); pk.y = f2b(p1); pk.z = f2b(p2); pk.w = f2b(p3);
                *(short4*)(Pw + l15 * 80 + kn * 16 + quad * 4) = pk;
            }
            psum[qt] += ps;
#pragma unroll
            for (int ks = 0; ks < 2; ks++) {
                bf16x8 pa = *(const bf16x8*)(Pw + l15 * 80 + ks * 32 + quad * 8);
#pragma unroll
                for (int on = 0; on < 4; on++)
                    oacc[qt][on] = __builtin_amdgcn_mfma_f32_16x16x32_bf16(
                        pa, vb[on][ks], oacc[qt][on], 0, 0, 0);
            }
        }
    }

    short* Op = attnO + (size_t)j * ELEM4M;
#pragma unroll
    for (int qt = 0; qt < 4; qt++) {
        float s = psum[qt];
        s += __shfl_xor(s, 16); s += __shfl_xor(s, 32);
        float inv = 1.0f / s;
        float invr[4];
#pragma unroll
        for (int r = 0; r < 4; r++) invr[r] = __shfl(inv, quad * 4 + r);
#pragma unroll
        for (int on = 0; on < 4; on++) {
            int col = h * 64 + on * 16 + l15;
#pragma unroll
            for (int r = 0; r < 4; r++) {
                int row = qrow0 + qt * 16 + quad * 4 + r;
                Op[(size_t)row * 1024 + col] = f2b(oacc[qt][on][r] * invr[r]);
            }
        }
    }
}

// ---------------- gate dot (g1 @ Wg2 + bg2), softmax-3, fuse, un-roll store
__global__ __launch_bounds__(256) void fuse_k(
    const short* __restrict__ g1, const short* __restrict__ fcat,
    const float* __restrict__ Wg2, const float* __restrict__ bg2,
    float* __restrict__ out)
{
    int row = blockIdx.x, tid = threadIdx.x;
    const short* gp = g1 + (size_t)row * 2048;
    float a0 = 0.f, a1 = 0.f, a2 = 0.f;
    for (int k = tid; k < 2048; k += 256) {
        float gv = b2f(gp[k]);
        a0 += gv * Wg2[k * 3 + 0];
        a1 += gv * Wg2[k * 3 + 1];
        a2 += gv * Wg2[k * 3 + 2];
    }
#pragma unroll
    for (int off = 1; off < 64; off <<= 1) {
        a0 += __shfl_xor(a0, off); a1 += __shfl_xor(a1, off); a2 += __shfl_xor(a2, off);
    }
    __shared__ float part[4][3];
    int wave = tid >> 6, lane = tid & 63;
    if (lane == 0) { part[wave][0] = a0; part[wave][1] = a1; part[wave][2] = a2; }
    __syncthreads();
    float g0 = part[0][0] + part[1][0] + part[2][0] + part[3][0] + bg2[0];
    float gA = part[0][1] + part[1][1] + part[2][1] + part[3][1] + bg2[1];
    float gB = part[0][2] + part[1][2] + part[2][2] + part[3][2] + bg2[2];
    float mx = fmaxf(g0, fmaxf(gA, gB));
    float e0 = __expf(g0 - mx), e1 = __expf(gA - mx), e2 = __expf(gB - mx);
    float inv = 1.0f / (e0 + e1 + e2);
    e0 *= inv; e1 *= inv; e2 *= inv;

    int b = row >> 11, tp = (row >> 6) & 31, l = row & 63;
    size_t orow = (size_t)(b * 32 + ((tp + 4) & 31)) * 64 + l;
    const short* f0 = fcat + (size_t)row * 3072;
    float* op = out + orow * 1024;
    for (int c = tid; c < 1024; c += 256)
        op[c] = e0 * b2f(f0[c]) + e1 * b2f(f0[1024 + c]) + e2 * b2f(f0[2048 + c]);
}

extern "C" void kernel_launch(void* const* d_in, const int* in_sizes, int n_in,
                              void* d_out, int out_size, void* d_ws, size_t ws_size,
                              hipStream_t stream)
{
    const float* audio = (const float*)d_in[0];
    const float* video = (const float*)d_in[1];
    const float* image = (const float*)d_in[2];
    const float* Wq = (const float*)d_in[3];
    const float* Wk = (const float*)d_in[4];
    const float* Wv = (const float*)d_in[5];
    const float* Wp = (const float*)d_in[6];
    const float* bq = (const float*)d_in[7];
    const float* bk = (const float*)d_in[8];
    const float* bv = (const float*)d_in[9];
    const float* bp = (const float*)d_in[10];
    const float* qn = (const float*)d_in[11];
    const float* kn = (const float*)d_in[12];
    const float* rpb = (const float*)d_in[13];
    const float* Wg1 = (const float*)d_in[14];
    const float* bg1 = (const float*)d_in[15];
    const float* Wg2 = (const float*)d_in[16];
    const float* bg2 = (const float*)d_in[17];
    float* out = (float*)d_out;

    short* ws = (short*)d_ws;
    short* rolled = ws;                                  // 3 * 4M
    short* Wt     = rolled + 3 * ELEM4M;                 // 12 * 1M
    short* Wg1t   = Wt + 12 * ELEM1M;                    // 6M  [2048][3072]
    short* qkv    = Wg1t + 6 * ELEM1M;                   // 9 * 4M (Q,K,V x3)
    short* attnO  = qkv + 9 * ELEM4M;                    // 3 * 4M
    short* fcat   = attnO + 3 * ELEM4M;                  // 4096*3072
    short* VtBuf  = fcat;                                // overlay: Vt dead before fcat written
    short* g1buf  = qkv;                                 // overlay: qkv dead after attn

    cast_roll_k<<<dim3(4096, 3), 256, 0, stream>>>(audio, video, image, rolled);
    transpose_qkvp_k<<<dim3(32, 32, 12), dim3(32, 8), 0, stream>>>(Wq, Wk, Wv, Wp, Wt);
    transpose_wg1_k<<<dim3(64, 96), dim3(32, 8), 0, stream>>>(Wg1, Wg1t);
    gemm_qkv_k<<<dim3(32, 8, 9), 256, 0, stream>>>(
        rolled, rolled + ELEM4M, rolled + 2 * ELEM4M, Wt, bq, bk, bv, qn, kn, qkv);
    transpose_v_k<<<dim3(16, 64, 3), 256, 0, stream>>>(qkv + 6 * ELEM4M, VtBuf);
    attn_k<<<dim3(2, 128, 3), 256, 0, stream>>>(qkv, VtBuf, rpb, attnO);
    gemm_out_k<<<dim3(32, 8, 3), 256, 0, stream>>>(
        attnO, Wt + 9 * ELEM1M, bp, rolled, rolled + ELEM4M, rolled + 2 * ELEM4M, fcat);
    gemm_gate_k<<<dim3(32, 16), 256, 0, stream>>>(fcat, Wg1t, bg1, g1buf);
    fuse_k<<<4096, 256, 0, stream>>>(g1buf, fcat, Wg2, bg2, out);
}